// Round 13
// baseline (26.725 us; speedup 1.0000x reference)
//
#include <hip/hip_runtime.h>

#define NB 8
#define NT 2048
#define ND 1024
#define NS 512
#define NW 16

typedef float f32x4 __attribute__((ext_vector_type(4)));

// Persistent-wave + per-XCD work queue.
// Grid = 2048 one-wave blocks. Block i: static span (b=i&7, s=i>>3 in 0..255),
// then pops spans s=256+n from counter[b] (per-XCD queue, 64B spacing).
// Rationale: round-12 grid was fully resident -> no dispatch refill; per-CU
// work is a random sum (mean 64 rows, sigma 17) and the kernel waited on the
// ~1.7x-mean tail CU. Span-granular stealing within each XCD flattens that
// while keeping all of batch b's gathers on XCD b (L2 locality).
// Quad-row main loop: 16 loads in flight, 4 interleaved butterfly chains.
// Unnormalized-exp softmax; esum==0 -> zeros (reference all-masked semantics).
__global__ __launch_bounds__(64) void span_attn_kernel(
    const float* __restrict__ text,   // [B, T, D]
    const int*   __restrict__ wi,     // [B, S, W]
    const int*   __restrict__ wm,     // [B, S, W]
    const int*   __restrict__ wim,    // [B, S]
    const float* __restrict__ att_w,  // [D]
    const float* __restrict__ att_b,  // [1]
    float*       __restrict__ out,    // [B, S, D]
    unsigned*    __restrict__ counters) // 8 x (64B-spaced) pop counters
{
    const int lane = threadIdx.x;
    const int b    = blockIdx.x & (NB - 1);
    unsigned* ctr  = counters + b * 16;

    f32x4 wfrag[4];
    #pragma unroll
    for (int k = 0; k < 4; ++k)
        wfrag[k] = *reinterpret_cast<const f32x4*>(att_w + 4 * lane + 256 * k);
    const float bias = att_b[0];
    const float* tbase = text + (size_t)b * NT * ND + 4 * lane;

    int s = blockIdx.x >> 3;               // static first span: 0..255

    while (true) {
        const int bs = b * NS + s;
        float* orow = out + (size_t)bs * ND + 4 * lane;

        if (wim[bs] == 0) {                 // span exactly 0: store and move on
            #pragma unroll
            for (int k = 0; k < 4; ++k)
                __builtin_nontemporal_store((f32x4){0.f, 0.f, 0.f, 0.f},
                    reinterpret_cast<f32x4*>(orow + 256 * k));
        } else {
            const int* wip = wi + (size_t)bs * NW;
            const int* wmp = wm + (size_t)bs * NW;

            unsigned mask = 0;
            #pragma unroll
            for (int q = 0; q < 4; ++q) {
                const int4 mv = *reinterpret_cast<const int4*>(wmp + 4 * q);
                mask |= (mv.x != 0 ? 1u : 0u) << (4 * q + 0);
                mask |= (mv.y != 0 ? 1u : 0u) << (4 * q + 1);
                mask |= (mv.z != 0 ? 1u : 0u) << (4 * q + 2);
                mask |= (mv.w != 0 ? 1u : 0u) << (4 * q + 3);
            }

            f32x4 acc[4];
            #pragma unroll
            for (int k = 0; k < 4; ++k) acc[k] = (f32x4){0.f, 0.f, 0.f, 0.f};
            float esum = 0.0f;

            // ---- quad main loop: 16 loads in flight, 4 shuffle chains ----
            while (__popc(mask) >= 4) {
                const int r0 = __builtin_ctz(mask); mask &= mask - 1;
                const int r1 = __builtin_ctz(mask); mask &= mask - 1;
                const int r2 = __builtin_ctz(mask); mask &= mask - 1;
                const int r3 = __builtin_ctz(mask); mask &= mask - 1;
                const int i0 = wip[r0], i1 = wip[r1], i2 = wip[r2], i3 = wip[r3];
                const float* s0 = tbase + (size_t)(i0 > 0 ? i0 : 0) * ND;
                const float* s1 = tbase + (size_t)(i1 > 0 ? i1 : 0) * ND;
                const float* s2 = tbase + (size_t)(i2 > 0 ? i2 : 0) * ND;
                const float* s3 = tbase + (size_t)(i3 > 0 ? i3 : 0) * ND;
                f32x4 f0[4], f1[4], f2[4], f3[4];
                #pragma unroll
                for (int k = 0; k < 4; ++k) {
                    f0[k] = *reinterpret_cast<const f32x4*>(s0 + 256 * k);
                    f1[k] = *reinterpret_cast<const f32x4*>(s1 + 256 * k);
                    f2[k] = *reinterpret_cast<const f32x4*>(s2 + 256 * k);
                    f3[k] = *reinterpret_cast<const f32x4*>(s3 + 256 * k);
                }
                float d0 = 0.f, d1 = 0.f, d2 = 0.f, d3 = 0.f;
                #pragma unroll
                for (int k = 0; k < 4; ++k) {
                    d0 += f0[k].x * wfrag[k].x + f0[k].y * wfrag[k].y
                        + f0[k].z * wfrag[k].z + f0[k].w * wfrag[k].w;
                    d1 += f1[k].x * wfrag[k].x + f1[k].y * wfrag[k].y
                        + f1[k].z * wfrag[k].z + f1[k].w * wfrag[k].w;
                    d2 += f2[k].x * wfrag[k].x + f2[k].y * wfrag[k].y
                        + f2[k].z * wfrag[k].z + f2[k].w * wfrag[k].w;
                    d3 += f3[k].x * wfrag[k].x + f3[k].y * wfrag[k].y
                        + f3[k].z * wfrag[k].z + f3[k].w * wfrag[k].w;
                }
                #pragma unroll
                for (int sh = 1; sh < 64; sh <<= 1) {
                    d0 += __shfl_xor(d0, sh);
                    d1 += __shfl_xor(d1, sh);
                    d2 += __shfl_xor(d2, sh);
                    d3 += __shfl_xor(d3, sh);
                }
                const float e0 = __expf(d0 + bias);
                const float e1 = __expf(d1 + bias);
                const float e2 = __expf(d2 + bias);
                const float e3 = __expf(d3 + bias);
                esum += (e0 + e1) + (e2 + e3);
                #pragma unroll
                for (int k = 0; k < 4; ++k) {
                    acc[k].x += e0 * f0[k].x + e1 * f1[k].x + e2 * f2[k].x + e3 * f3[k].x;
                    acc[k].y += e0 * f0[k].y + e1 * f1[k].y + e2 * f2[k].y + e3 * f3[k].y;
                    acc[k].z += e0 * f0[k].z + e1 * f1[k].z + e2 * f2[k].z + e3 * f3[k].z;
                    acc[k].w += e0 * f0[k].w + e1 * f1[k].w + e2 * f2[k].w + e3 * f3[k].w;
                }
            }

            // ---- pair tail ----
            if (__popc(mask) >= 2) {
                const int r0 = __builtin_ctz(mask); mask &= mask - 1;
                const int r1 = __builtin_ctz(mask); mask &= mask - 1;
                const int i0 = wip[r0], i1 = wip[r1];
                const float* s0 = tbase + (size_t)(i0 > 0 ? i0 : 0) * ND;
                const float* s1 = tbase + (size_t)(i1 > 0 ? i1 : 0) * ND;
                f32x4 f0[4], f1[4];
                #pragma unroll
                for (int k = 0; k < 4; ++k) {
                    f0[k] = *reinterpret_cast<const f32x4*>(s0 + 256 * k);
                    f1[k] = *reinterpret_cast<const f32x4*>(s1 + 256 * k);
                }
                float d0 = 0.f, d1 = 0.f;
                #pragma unroll
                for (int k = 0; k < 4; ++k) {
                    d0 += f0[k].x * wfrag[k].x + f0[k].y * wfrag[k].y
                        + f0[k].z * wfrag[k].z + f0[k].w * wfrag[k].w;
                    d1 += f1[k].x * wfrag[k].x + f1[k].y * wfrag[k].y
                        + f1[k].z * wfrag[k].z + f1[k].w * wfrag[k].w;
                }
                #pragma unroll
                for (int sh = 1; sh < 64; sh <<= 1) {
                    d0 += __shfl_xor(d0, sh);
                    d1 += __shfl_xor(d1, sh);
                }
                const float e0 = __expf(d0 + bias);
                const float e1 = __expf(d1 + bias);
                esum += e0 + e1;
                #pragma unroll
                for (int k = 0; k < 4; ++k) {
                    acc[k].x += e0 * f0[k].x + e1 * f1[k].x;
                    acc[k].y += e0 * f0[k].y + e1 * f1[k].y;
                    acc[k].z += e0 * f0[k].z + e1 * f1[k].z;
                    acc[k].w += e0 * f0[k].w + e1 * f1[k].w;
                }
            }

            // ---- single tail ----
            if (mask) {
                const int r0 = __builtin_ctz(mask);
                const int i0 = wip[r0];
                const float* s0 = tbase + (size_t)(i0 > 0 ? i0 : 0) * ND;
                f32x4 f0[4];
                #pragma unroll
                for (int k = 0; k < 4; ++k)
                    f0[k] = *reinterpret_cast<const f32x4*>(s0 + 256 * k);
                float d0 = 0.f;
                #pragma unroll
                for (int k = 0; k < 4; ++k)
                    d0 += f0[k].x * wfrag[k].x + f0[k].y * wfrag[k].y
                        + f0[k].z * wfrag[k].z + f0[k].w * wfrag[k].w;
                #pragma unroll
                for (int sh = 1; sh < 64; sh <<= 1)
                    d0 += __shfl_xor(d0, sh);
                const float e0 = __expf(d0 + bias);
                esum += e0;
                #pragma unroll
                for (int k = 0; k < 4; ++k) {
                    acc[k].x += e0 * f0[k].x;
                    acc[k].y += e0 * f0[k].y;
                    acc[k].z += e0 * f0[k].z;
                    acc[k].w += e0 * f0[k].w;
                }
            }

            const float inv = esum > 0.0f ? 1.0f / esum : 0.0f;
            #pragma unroll
            for (int k = 0; k < 4; ++k) {
                f32x4 o = acc[k];
                o.x *= inv; o.y *= inv; o.z *= inv; o.w *= inv;
                __builtin_nontemporal_store(o,
                    reinterpret_cast<f32x4*>(orow + 256 * k));
            }
        }

        // ---- pop next span for this XCD's batch ----
        unsigned n = 0;
        if (lane == 0) n = atomicAdd(ctr, 1u);
        n = (unsigned)__shfl((int)n, 0);
        if (n >= (unsigned)(NS - 256)) break;
        s = 256 + (int)n;
    }
}

extern "C" void kernel_launch(void* const* d_in, const int* in_sizes, int n_in,
                              void* d_out, int out_size, void* d_ws, size_t ws_size,
                              hipStream_t stream) {
    const float* text  = (const float*)d_in[0];
    // d_in[1] = contextualized_embedding: unused by the reference.
    const int*   wi    = (const int*)d_in[2];
    const int*   wm    = (const int*)d_in[3];
    const int*   wim   = (const int*)d_in[4];
    const float* att_w = (const float*)d_in[5];
    const float* att_b = (const float*)d_in[6];
    float*       out   = (float*)d_out;
    unsigned*    ctrs  = (unsigned*)d_ws;   // 8 counters, 64B spacing

    hipMemsetAsync(d_ws, 0, 8 * 16 * sizeof(unsigned), stream);
    span_attn_kernel<<<dim3(2048), dim3(64), 0, stream>>>(
        text, wi, wm, wim, att_w, att_b, out, ctrs);
}

// Round 14
// 15.483 us; speedup vs baseline: 1.7261x; 1.7261x over previous
//
#include <hip/hip_runtime.h>

#define NB 8
#define NT 2048
#define ND 1024
#define NS 512
#define NW 16

typedef float f32x4 __attribute__((ext_vector_type(4)));

// REVERT to round-12 (best: 15.47us). Round-13's per-XCD atomic work queue
// regressed to 26.7us: 256 blocks/batch serializing on one counter line +
// dependent pop between spans + extra memset dispatch.
// Evidence that this structure is at the gather-path delivered-BW ceiling:
//   round 11 (pair, ~90 VGPR, ~20 waves/CU)  = 15.6us
//   round 12 (quad, ~130 VGPR, ~12-16 w/CU)  = 15.5us  <- occupancy x1.5,
//   MLP x2 between them: both null. Dynamic balancing: regression.
// One WAVE per span; grid 4096; lane l covers float cols 4l + 256k.
// Quad-row main loop: 16 loads in flight, 4 interleaved butterfly chains.
// Unnormalized-exp softmax; esum==0 -> zeros (reference all-masked semantics).
// XCD swizzle: b = blockIdx & 7 keeps each XCD's gathers inside text[b].
__global__ __launch_bounds__(64) void span_attn_kernel(
    const float* __restrict__ text,   // [B, T, D]
    const int*   __restrict__ wi,     // [B, S, W]
    const int*   __restrict__ wm,     // [B, S, W]
    const int*   __restrict__ wim,    // [B, S]
    const float* __restrict__ att_w,  // [D]
    const float* __restrict__ att_b,  // [1]
    float*       __restrict__ out)    // [B, S, D]
{
    const int b    = blockIdx.x & (NB - 1);
    const int s    = blockIdx.x >> 3;
    const int bs   = b * NS + s;
    const int lane = threadIdx.x;

    float* orow = out + (size_t)bs * ND + 4 * lane;

    if (wim[bs] == 0) {                    // uniform: span is exactly 0
        #pragma unroll
        for (int k = 0; k < 4; ++k)
            __builtin_nontemporal_store((f32x4){0.f, 0.f, 0.f, 0.f},
                reinterpret_cast<f32x4*>(orow + 256 * k));
        return;
    }

    const int* wip = wi + (size_t)bs * NW;
    const int* wmp = wm + (size_t)bs * NW;

    unsigned mkbits = 0;
    #pragma unroll
    for (int q = 0; q < 4; ++q) {
        const int4 mv = *reinterpret_cast<const int4*>(wmp + 4 * q);
        mkbits |= (mv.x != 0 ? 1u : 0u) << (4 * q + 0);
        mkbits |= (mv.y != 0 ? 1u : 0u) << (4 * q + 1);
        mkbits |= (mv.z != 0 ? 1u : 0u) << (4 * q + 2);
        mkbits |= (mv.w != 0 ? 1u : 0u) << (4 * q + 3);
    }

    f32x4 wfrag[4];
    #pragma unroll
    for (int k = 0; k < 4; ++k)
        wfrag[k] = *reinterpret_cast<const f32x4*>(att_w + 4 * lane + 256 * k);
    const float bias = att_b[0];

    const float* tbase = text + (size_t)b * NT * ND + 4 * lane;

    f32x4 acc[4];
    #pragma unroll
    for (int k = 0; k < 4; ++k) acc[k] = (f32x4){0.f, 0.f, 0.f, 0.f};
    float esum = 0.0f;

    unsigned mask = mkbits;

    // ---- quad main loop: 16 loads in flight, 4 shuffle chains ----
    while (__popc(mask) >= 4) {
        const int r0 = __builtin_ctz(mask); mask &= mask - 1;
        const int r1 = __builtin_ctz(mask); mask &= mask - 1;
        const int r2 = __builtin_ctz(mask); mask &= mask - 1;
        const int r3 = __builtin_ctz(mask); mask &= mask - 1;
        const int i0 = wip[r0], i1 = wip[r1], i2 = wip[r2], i3 = wip[r3];
        const float* s0 = tbase + (size_t)(i0 > 0 ? i0 : 0) * ND;
        const float* s1 = tbase + (size_t)(i1 > 0 ? i1 : 0) * ND;
        const float* s2 = tbase + (size_t)(i2 > 0 ? i2 : 0) * ND;
        const float* s3 = tbase + (size_t)(i3 > 0 ? i3 : 0) * ND;
        f32x4 f0[4], f1[4], f2[4], f3[4];
        #pragma unroll
        for (int k = 0; k < 4; ++k) {
            f0[k] = *reinterpret_cast<const f32x4*>(s0 + 256 * k);
            f1[k] = *reinterpret_cast<const f32x4*>(s1 + 256 * k);
            f2[k] = *reinterpret_cast<const f32x4*>(s2 + 256 * k);
            f3[k] = *reinterpret_cast<const f32x4*>(s3 + 256 * k);
        }
        float d0 = 0.f, d1 = 0.f, d2 = 0.f, d3 = 0.f;
        #pragma unroll
        for (int k = 0; k < 4; ++k) {
            d0 += f0[k].x * wfrag[k].x + f0[k].y * wfrag[k].y
                + f0[k].z * wfrag[k].z + f0[k].w * wfrag[k].w;
            d1 += f1[k].x * wfrag[k].x + f1[k].y * wfrag[k].y
                + f1[k].z * wfrag[k].z + f1[k].w * wfrag[k].w;
            d2 += f2[k].x * wfrag[k].x + f2[k].y * wfrag[k].y
                + f2[k].z * wfrag[k].z + f2[k].w * wfrag[k].w;
            d3 += f3[k].x * wfrag[k].x + f3[k].y * wfrag[k].y
                + f3[k].z * wfrag[k].z + f3[k].w * wfrag[k].w;
        }
        #pragma unroll
        for (int sh = 1; sh < 64; sh <<= 1) {
            d0 += __shfl_xor(d0, sh);
            d1 += __shfl_xor(d1, sh);
            d2 += __shfl_xor(d2, sh);
            d3 += __shfl_xor(d3, sh);
        }
        const float e0 = __expf(d0 + bias);
        const float e1 = __expf(d1 + bias);
        const float e2 = __expf(d2 + bias);
        const float e3 = __expf(d3 + bias);
        esum += (e0 + e1) + (e2 + e3);
        #pragma unroll
        for (int k = 0; k < 4; ++k) {
            acc[k].x += e0 * f0[k].x + e1 * f1[k].x + e2 * f2[k].x + e3 * f3[k].x;
            acc[k].y += e0 * f0[k].y + e1 * f1[k].y + e2 * f2[k].y + e3 * f3[k].y;
            acc[k].z += e0 * f0[k].z + e1 * f1[k].z + e2 * f2[k].z + e3 * f3[k].z;
            acc[k].w += e0 * f0[k].w + e1 * f1[k].w + e2 * f2[k].w + e3 * f3[k].w;
        }
    }

    // ---- pair tail ----
    if (__popc(mask) >= 2) {
        const int r0 = __builtin_ctz(mask); mask &= mask - 1;
        const int r1 = __builtin_ctz(mask); mask &= mask - 1;
        const int i0 = wip[r0], i1 = wip[r1];
        const float* s0 = tbase + (size_t)(i0 > 0 ? i0 : 0) * ND;
        const float* s1 = tbase + (size_t)(i1 > 0 ? i1 : 0) * ND;
        f32x4 f0[4], f1[4];
        #pragma unroll
        for (int k = 0; k < 4; ++k) {
            f0[k] = *reinterpret_cast<const f32x4*>(s0 + 256 * k);
            f1[k] = *reinterpret_cast<const f32x4*>(s1 + 256 * k);
        }
        float d0 = 0.f, d1 = 0.f;
        #pragma unroll
        for (int k = 0; k < 4; ++k) {
            d0 += f0[k].x * wfrag[k].x + f0[k].y * wfrag[k].y
                + f0[k].z * wfrag[k].z + f0[k].w * wfrag[k].w;
            d1 += f1[k].x * wfrag[k].x + f1[k].y * wfrag[k].y
                + f1[k].z * wfrag[k].z + f1[k].w * wfrag[k].w;
        }
        #pragma unroll
        for (int sh = 1; sh < 64; sh <<= 1) {
            d0 += __shfl_xor(d0, sh);
            d1 += __shfl_xor(d1, sh);
        }
        const float e0 = __expf(d0 + bias);
        const float e1 = __expf(d1 + bias);
        esum += e0 + e1;
        #pragma unroll
        for (int k = 0; k < 4; ++k) {
            acc[k].x += e0 * f0[k].x + e1 * f1[k].x;
            acc[k].y += e0 * f0[k].y + e1 * f1[k].y;
            acc[k].z += e0 * f0[k].z + e1 * f1[k].z;
            acc[k].w += e0 * f0[k].w + e1 * f1[k].w;
        }
    }

    // ---- single tail ----
    if (mask) {
        const int r0 = __builtin_ctz(mask);
        const int i0 = wip[r0];
        const float* s0 = tbase + (size_t)(i0 > 0 ? i0 : 0) * ND;
        f32x4 f0[4];
        #pragma unroll
        for (int k = 0; k < 4; ++k)
            f0[k] = *reinterpret_cast<const f32x4*>(s0 + 256 * k);
        float d0 = 0.f;
        #pragma unroll
        for (int k = 0; k < 4; ++k)
            d0 += f0[k].x * wfrag[k].x + f0[k].y * wfrag[k].y
                + f0[k].z * wfrag[k].z + f0[k].w * wfrag[k].w;
        #pragma unroll
        for (int sh = 1; sh < 64; sh <<= 1)
            d0 += __shfl_xor(d0, sh);
        const float e0 = __expf(d0 + bias);
        esum += e0;
        #pragma unroll
        for (int k = 0; k < 4; ++k) {
            acc[k].x += e0 * f0[k].x;
            acc[k].y += e0 * f0[k].y;
            acc[k].z += e0 * f0[k].z;
            acc[k].w += e0 * f0[k].w;
        }
    }

    const float inv = esum > 0.0f ? 1.0f / esum : 0.0f;
    #pragma unroll
    for (int k = 0; k < 4; ++k) {
        f32x4 o = acc[k];
        o.x *= inv; o.y *= inv; o.z *= inv; o.w *= inv;
        __builtin_nontemporal_store(o, reinterpret_cast<f32x4*>(orow + 256 * k));
    }
}

extern "C" void kernel_launch(void* const* d_in, const int* in_sizes, int n_in,
                              void* d_out, int out_size, void* d_ws, size_t ws_size,
                              hipStream_t stream) {
    const float* text  = (const float*)d_in[0];
    // d_in[1] = contextualized_embedding: unused by the reference.
    const int*   wi    = (const int*)d_in[2];
    const int*   wm    = (const int*)d_in[3];
    const int*   wim   = (const int*)d_in[4];
    const float* att_w = (const float*)d_in[5];
    const float* att_b = (const float*)d_in[6];
    float*       out   = (float*)d_out;

    span_attn_kernel<<<dim3(NB * NS), dim3(64), 0, stream>>>(
        text, wi, wm, wim, att_w, att_b, out);
}